// Round 4
// baseline (49.586 us; speedup 1.0000x reference)
//
#include <hip/hip_runtime.h>

// QueryAndGroup: ball_query(r=0.2, nsample=32) + group xyz (centered) + group features.
// B=4, N=16384, M=2048, C=64. Output (B, 67, M, 32) f32.
//
// Kernel 1 (scan): one wave per query, no featT needed. Scans xyz in 256-pt
//   groups with next-group register prefetch (dependent chain ~= max(load,
//   process) instead of sum). Collects first-32 in-radius indices into LDS via
//   ballot/prefix-popcount, writes them coalesced to idxws, and emits the 3
//   centered-xyz output channels directly (tiny: 3.1 MB).
// Kernel 2 (gather): one block per (b, channel, query-half). Stages the 64 KB
//   channel row feat[b][c][:] into LDS (coalesced float4), then serves 32K
//   random 4B gathers from LDS -- word-addressed, zero cache-line
//   amplification -- with int4 idx loads and float4 coalesced stores.
//   This deletes the featT transpose round-trip (33.6 MB HBM) entirely.

#define WPB 4
constexpr int Bc = 4, Nc = 16384, Mc = 2048, Cc = 64, Sc = 32;
constexpr int SCAN_BLOCKS   = (Bc * Mc) / WPB;  // 2048
constexpr int GATHER_BLOCKS = Bc * Cc * 2;      // 512 (query halves)

__global__ __launch_bounds__(256) void scan_kernel(
    const float* __restrict__ xyz,      // (B, N, 3)
    const float* __restrict__ new_xyz,  // (B, M, 3)
    int* __restrict__ idxws,            // (B*M, 32)
    float* __restrict__ out)            // (B, 67, M, 32); writes channels 0..2
{
#pragma clang fp contract(off)
    const int lane = threadIdx.x & 63;
    const int wv   = threadIdx.x >> 6;
    const int q    = blockIdx.x * WPB + wv;
    const int b    = q >> 11;            // / Mc
    const int m    = q & (Mc - 1);

    __shared__ int sidx[WPB][Sc];

    const float r2 = 0.2f * 0.2f;
    const float* nz = new_xyz + (size_t)(b * Mc + m) * 3;
    const float qx = nz[0], qy = nz[1], qz = nz[2];
    const float* xb = xyz + (size_t)b * Nc * 3;

    int count = 0, firstIdx = 0;
    const unsigned long long lt = (1ull << lane) - 1ull;

    float px[4], py[4], pz[4];
    #pragma unroll
    for (int u = 0; u < 4; ++u) {
        const float* pp = xb + (size_t)(u * 64 + lane) * 3;
        px[u] = pp[0]; py[u] = pp[1]; pz[u] = pp[2];
    }
    for (int base = 0; base < Nc; base += 256) {
        // Prefetch next group (clamped; wasted on last iter / early exit).
        const int nb = (base + 256 < Nc) ? base + 256 : base;
        float nx[4], ny[4], nzv[4];
        #pragma unroll
        for (int u = 0; u < 4; ++u) {
            const float* pp = xb + (size_t)(nb + u * 64 + lane) * 3;
            nx[u] = pp[0]; ny[u] = pp[1]; nzv[u] = pp[2];
        }
        #pragma unroll
        for (int u = 0; u < 4; ++u) {
            const float dx = qx - px[u], dy = qy - py[u], dz = qz - pz[u];
            float d2 = dx * dx + dy * dy;   // no fma: match np/jax f32 rounding
            d2 = d2 + dz * dz;
            const bool in = d2 < r2;
            const unsigned long long mask = __ballot(in);
            if (in) {
                const int slot = count + __popcll(mask & lt);
                if (slot < Sc) sidx[wv][slot] = base + u * 64 + lane;
            }
            if (count == 0 && mask != 0ull)
                firstIdx = base + u * 64 + __builtin_ctzll(mask);
            count += __popcll(mask);
        }
        if (count >= Sc) break;             // wave-uniform
        #pragma unroll
        for (int u = 0; u < 4; ++u) { px[u] = nx[u]; py[u] = ny[u]; pz[u] = nzv[u]; }
    }
    {
        const int start = count < Sc ? count : Sc;
        if (start + lane < Sc) sidx[wv][start + lane] = firstIdx;
    }
    // Same-wave LDS visibility (waves are independent; no block barrier).
    asm volatile("s_waitcnt lgkmcnt(0)" ::: "memory");

    // Coalesced idx write for the gather kernel.
    if (lane < Sc) idxws[(size_t)q * Sc + lane] = sidx[wv][lane];

    // Centered-xyz channels 0..2.
    const int s     = lane & 31;
    const int chalf = lane >> 5;
    const int myid  = sidx[wv][s];
    float* ob = out + ((size_t)b * 67 * Mc + m) * Sc;
    ob[(size_t)chalf * (Mc * Sc) + s] = xb[(size_t)myid * 3 + chalf] - (chalf ? qy : qx);
    if (chalf == 0)
        ob[(size_t)2 * (Mc * Sc) + s] = xb[(size_t)myid * 3 + 2] - qz;
}

__global__ __launch_bounds__(256) void gather_kernel(
    const float* __restrict__ feat,   // (B, C, N)
    const int* __restrict__ idxws,    // (B*M, 32)
    float* __restrict__ out)          // (B, 67, M, 32); writes channels 3..66
{
    __shared__ float frow[Nc];        // one 64 KB channel row
    const int bi = blockIdx.x;        // 0..511
    const int b  = bi >> 7;           // / (Cc*2)
    const int c  = (bi >> 1) & (Cc - 1);
    const int qc = bi & 1;            // which half of the queries
    const int tid = threadIdx.x;

    const float* src = feat + ((size_t)b * Cc + c) * Nc;
    #pragma unroll
    for (int i = 0; i < Nc / 1024; ++i) {      // 16 iters: coalesced float4
        const int o = i * 1024 + tid * 4;
        *(float4*)&frow[o] = *(const float4*)&src[o];
    }
    __syncthreads();

    const int m0 = qc * (Mc / 2);
    const int* ib = idxws + ((size_t)b * Mc + m0) * Sc;
    float* op = out + ((size_t)(b * 67 + 3 + c) * Mc + m0) * Sc;

    #pragma unroll 4
    for (int i = 0; i < 32; ++i) {
        const int p = i * 1024 + tid * 4;      // 4 consecutive (m,s) pairs
        const int4 id4 = *(const int4*)&ib[p]; // coalesced 16B idx load
        float4 v;
        v.x = frow[id4.x]; v.y = frow[id4.y];  // word-addressed LDS gather
        v.z = frow[id4.z]; v.w = frow[id4.w];
        *(float4*)&op[p] = v;                  // coalesced 16B store
    }
}

// Fallback (ws too small for idx): R1's fused kernel with direct (C,N) gather.
__global__ __launch_bounds__(256) void qg_fallback_kernel(
    const float* __restrict__ xyz, const float* __restrict__ new_xyz,
    const float* __restrict__ feat, float* __restrict__ out)
{
#pragma clang fp contract(off)
    const int lane = threadIdx.x & 63;
    const int wv   = threadIdx.x >> 6;
    const int q    = blockIdx.x * WPB + wv;
    const int b    = q >> 11;
    const int m    = q & (Mc - 1);
    __shared__ int sidx[WPB][Sc];
    const float r2 = 0.2f * 0.2f;
    const float* nz = new_xyz + (size_t)(b * Mc + m) * 3;
    const float qx = nz[0], qy = nz[1], qz = nz[2];
    const float* xb = xyz + (size_t)b * Nc * 3;
    int count = 0, firstIdx = 0;
    const unsigned long long lt = (1ull << lane) - 1ull;
    for (int base = 0; base < Nc; base += 64) {
        const int i = base + lane;
        const float px = xb[i * 3], py = xb[i * 3 + 1], pz = xb[i * 3 + 2];
        const float dx = qx - px, dy = qy - py, dz = qz - pz;
        float d2 = dx * dx + dy * dy; d2 = d2 + dz * dz;
        const bool in = d2 < r2;
        const unsigned long long mask = __ballot(in);
        if (in) {
            const int slot = count + __popcll(mask & lt);
            if (slot < Sc) sidx[wv][slot] = i;
        }
        if (count == 0 && mask != 0ull) firstIdx = base + __builtin_ctzll(mask);
        count += __popcll(mask);
        if (count >= Sc) break;
    }
    const int start = count < Sc ? count : Sc;
    if (start + lane < Sc) sidx[wv][start + lane] = firstIdx;
    asm volatile("s_waitcnt lgkmcnt(0)" ::: "memory");
    const int s = lane & 31, chalf = lane >> 5;
    const int myid = sidx[wv][s];
    float* ob = out + ((size_t)b * 67 * Mc + m) * Sc;
    #pragma unroll
    for (int it = 0; it < 2; ++it) {
        const int c = it * 2 + chalf;
        if (c < 3) {
            const float ctr = (c == 0) ? qx : (c == 1) ? qy : qz;
            ob[(size_t)c * (Mc * Sc) + s] = xb[(size_t)myid * 3 + c] - ctr;
        }
    }
    const float* fb = feat + (size_t)b * Cc * Nc;
    #pragma unroll
    for (int it = 0; it < 32; ++it) {
        const int c = it * 2 + chalf;
        ob[(size_t)(3 + c) * (Mc * Sc) + s] = fb[(size_t)c * Nc + myid];
    }
}

extern "C" void kernel_launch(void* const* d_in, const int* in_sizes, int n_in,
                              void* d_out, int out_size, void* d_ws, size_t ws_size,
                              hipStream_t stream) {
    const float* xyz     = (const float*)d_in[0];
    const float* new_xyz = (const float*)d_in[1];
    const float* feat    = (const float*)d_in[2];
    float* out           = (float*)d_out;

    const size_t idx_bytes = (size_t)Bc * Mc * Sc * sizeof(int);  // 1 MB

    if (ws_size >= idx_bytes) {
        int* idxws = (int*)d_ws;
        hipLaunchKernelGGL(scan_kernel, dim3(SCAN_BLOCKS), dim3(256), 0, stream,
                           xyz, new_xyz, idxws, out);
        hipLaunchKernelGGL(gather_kernel, dim3(GATHER_BLOCKS), dim3(256), 0, stream,
                           feat, idxws, out);
    } else {
        hipLaunchKernelGGL(qg_fallback_kernel, dim3(SCAN_BLOCKS), dim3(256), 0, stream,
                           xyz, new_xyz, feat, out);
    }
}